// Round 10
// baseline (116.568 us; speedup 1.0000x reference)
//
#include <hip/hip_runtime.h>
#include <hip/hip_bf16.h>

// Problem constants
#define Bsz 16
#define Lsz 512
#define Dsz 768
#define Tsz 12
#define Asz 64
#define N1  1536   // Tsz*Asz*2
#define Msz 8192   // Bsz*Lsz

typedef __bf16 bf16;
typedef bf16 bf16x2 __attribute__((ext_vector_type(2)));
typedef bf16 bf16x4 __attribute__((ext_vector_type(4)));
typedef bf16 bf16x8 __attribute__((ext_vector_type(8)));
typedef float f32x4 __attribute__((ext_vector_type(4)));
typedef unsigned long long u64;

__device__ inline void load_lds16(const bf16* g, bf16* l) {
    __builtin_amdgcn_global_load_lds((const __attribute__((address_space(1))) void*)g,
                                     (__attribute__((address_space(3))) void*)l, 16, 0, 0);
}

// ---- fused prep: cvt_input | cvt_w (straight transpose) | rope tables | mask bits ----
__global__ __launch_bounds__(256) void prep_kernel(
    const float* __restrict__ in, const float* __restrict__ W,
    const int* __restrict__ mask,
    bf16* __restrict__ Abf, bf16* __restrict__ Wt,
    float* __restrict__ Tc, float* __restrict__ Ts, u64* __restrict__ Mbits) {
    int blk = blockIdx.x;
    if (blk < 6144) {                       // cvt_input: 8192*768/4 threads
        int i = blk * 256 + threadIdx.x;
        float4 v = ((const float4*)in)[i];
        bf16x4 o;
        o[0] = (bf16)v.x; o[1] = (bf16)v.y; o[2] = (bf16)v.z; o[3] = (bf16)v.w;
        ((bf16x4*)Abf)[i] = o;
    } else if (blk < 6720) {                // cvt_w: N1*(Dsz/8) threads
        int tid = (blk - 6144) * 256 + threadIdx.x;
        int n  = tid % N1;
        int k0 = (tid / N1) * 8;
        bf16x8 o;
#pragma unroll
        for (int j = 0; j < 8; ++j) o[j] = (bf16)W[(size_t)(k0 + j) * N1 + n];
        *(bf16x8*)(Wt + (size_t)n * Dsz + k0) = o;
    } else if (blk < 6848) {                // rope tables: 512*64 threads
        int tid = (blk - 6720) * 256 + threadIdx.x;
        int l = tid >> 6, a = tid & 63;
        float theta = expf(-0.28782313662425575f * (float)(a >> 1));  // 10000^(-(a>>1)/32)
        float pe = (float)l * theta;
        float s, c;
        sincosf(pe, &s, &c);
        Tc[tid] = c; Ts[tid] = s;
    } else {                                // mask bits: 16*512 threads
        int tid = (blk - 6848) * 256 + threadIdx.x;
        u64 bal = __ballot(mask[tid] > 0);
        if ((tid & 63) == 0) Mbits[tid >> 6] = bal;
    }
}

__device__ __forceinline__ void rope_row(bf16* P, const float* tc, const float* ts) {
    float v[64];
#pragma unroll
    for (int c8 = 0; c8 < 8; ++c8) {
        bf16x8 x = *(const bf16x8*)(P + c8 * 8);
#pragma unroll
        for (int j = 0; j < 8; ++j) v[c8 * 8 + j] = (float)x[j];
    }
#pragma unroll
    for (int c8 = 0; c8 < 8; ++c8) {
        bf16x8 o;
#pragma unroll
        for (int j = 0; j < 8; ++j) {
            const int a  = c8 * 8 + j;
            const int a2 = (a < 32) ? (2 * a + 1) : (2 * (a - 32));
            const float sg = (a < 32) ? -1.f : 1.f;
            o[j] = (bf16)(v[a] * tc[a] + sg * v[a2] * ts[a]);
        }
        *(bf16x8*)(P + c8 * 8) = o;
    }
}

// ---- Kernel A: per-(b,head) projection + rope -> Qr/Kr [192][512][64] bf16 ----
// 192 blocks x 512 thr. Proj: triple-buffered global_load_lds staging with
// XOR-swizzle (chunk c of row r holds global chunk c^((r>>1)&3)); counted vmcnt.
#define PBUF 40960   // A 32768 + W 8192 per staging buffer
__global__ __launch_bounds__(512) void proj_kernel(
    const bf16* __restrict__ Abf, const bf16* __restrict__ Wt,
    const float* __restrict__ bias,
    const float* __restrict__ Tc, const float* __restrict__ Ts,
    bf16* __restrict__ Qr, bf16* __restrict__ Kr) {
    __shared__ char smem[147456];
    bf16* Xq = (bf16*)smem;                  // [512][72]
    bf16* Xk = (bf16*)(smem + 73728);        // [512][72]

    const int bid = blockIdx.x;
    const int z  = (bid & 7) * 24 + (bid >> 3);   // XCD-chunked
    const int b  = z / Tsz, th = z % Tsz;

    const int tid = threadIdx.x;
    const int wave = tid >> 6, lane = tid & 63;
    const int l15 = lane & 15, hi = lane >> 4;
    const int wm = wave >> 1, wn = wave & 1;

    const bf16* Ab = Abf + (size_t)b * Lsz * Dsz;
    const bf16* Wb = Wt + (size_t)th * 128 * Dsz;
    const int lq = lane >> 2;
    const int schunk = ((lane & 3) ^ ((lane >> 3) & 3)) * 8;   // swizzled src chunk
    const int dchunk = (lane & 3) * 8;                          // linear dest chunk
    const int koff = (hi ^ ((l15 >> 1) & 3)) * 16;              // swizzled frag read

    f32x4 acc[8][4] = {};

#define PSTAGE(buf, kk)                                                         \
    do {                                                                        \
        bf16* As = (bf16*)(smem + (buf) * PBUF);                                \
        bf16* Ws = (bf16*)(smem + (buf) * PBUF + 32768);                        \
        _Pragma("unroll")                                                       \
        for (int i = 0; i < 4; ++i) {                                           \
            int ra = wave * 64 + i * 16 + lq;                                   \
            load_lds16(Ab + (size_t)ra * Dsz + (kk) + schunk, As + ra * 32 + dchunk); \
        }                                                                       \
        int rw = wave * 16 + lq;                                                \
        load_lds16(Wb + (size_t)rw * Dsz + (kk) + schunk, Ws + rw * 32 + dchunk); \
    } while (0)

    PSTAGE(0, 0);
    PSTAGE(1, 32);
    asm volatile("s_waitcnt vmcnt(5)" ::: "memory");
    __builtin_amdgcn_s_barrier();

    int cur = 0;
    for (int t = 0; t < 24; ++t) {
        int stg = cur + 2; if (stg >= 3) stg -= 3;
        if (t + 2 < 24) PSTAGE(stg, (t + 2) * 32);

        const char* As = smem + cur * PBUF;
        const char* Ws = smem + cur * PBUF + 32768;
        bf16x8 af[8], bw[4];
#pragma unroll
        for (int mf = 0; mf < 8; ++mf)
            af[mf] = *(const bf16x8*)(As + (wm * 128 + mf * 16 + l15) * 64 + koff);
#pragma unroll
        for (int nf = 0; nf < 4; ++nf)
            bw[nf] = *(const bf16x8*)(Ws + (wn * 64 + nf * 16 + l15) * 64 + koff);
#pragma unroll
        for (int mf = 0; mf < 8; ++mf)
#pragma unroll
            for (int nf = 0; nf < 4; ++nf)
                acc[mf][nf] = __builtin_amdgcn_mfma_f32_16x16x32_bf16(af[mf], bw[nf], acc[mf][nf], 0, 0, 0);

        if (t + 1 < 24) {
            if (t + 2 < 24) asm volatile("s_waitcnt vmcnt(5)" ::: "memory");
            else            asm volatile("s_waitcnt vmcnt(0)" ::: "memory");
            __builtin_amdgcn_s_barrier();
        }
        cur = cur + 1; if (cur >= 3) cur -= 3;
    }
#undef PSTAGE
    __syncthreads();    // staging dead; smem becomes Xq/Xk planes

    // acc (+bias) -> q/k planes. C/D: col=wn*64+nf*16+l15, row=wm*128+mf*16+hi*4+r
    {
        const int r0 = hi * 4;
#pragma unroll
        for (int nf = 0; nf < 4; ++nf) {
            const int c = wn * 64 + nf * 16 + l15;
            const float bv = bias[th * 128 + c];
            bf16* P = (c & 1) ? Xk : Xq;
            const int a = c >> 1;
#pragma unroll
            for (int mf = 0; mf < 8; ++mf) {
                const int rw = wm * 128 + mf * 16 + r0;
#pragma unroll
                for (int r = 0; r < 4; ++r)
                    P[(rw + r) * 72 + a] = (bf16)(acc[mf][nf][r] + bv);
            }
        }
    }
    __syncthreads();

    // rope in place (thread = row l)
    rope_row(Xq + tid * 72, Tc + tid * 64, Ts + tid * 64);
    rope_row(Xk + tid * 72, Tc + tid * 64, Ts + tid * 64);
    __syncthreads();

    // planes -> global Qr/Kr (coalesced: lanes 0-7 chunks of row, 1KB/wave/iter)
    bf16* qo = Qr + (size_t)z * Lsz * Asz;
    bf16* ko = Kr + (size_t)z * Lsz * Asz;
    for (int i = tid; i < 512 * 8; i += 512) {
        const int row = i >> 3, c8 = i & 7;
        *(bf16x8*)(qo + row * 64 + c8 * 8) = *(const bf16x8*)(Xq + row * 72 + c8 * 8);
        *(bf16x8*)(ko + row * 64 + c8 * 8) = *(const bf16x8*)(Xk + row * 72 + c8 * 8);
    }
}

// ---- Kernel B: QK^T + mask. Swapped operands (A=K,B=Q) -> float4 stores.
// Grid (8,8,192), 256 thr, no LDS -> high occupancy, self-staggered stores.
__global__ __launch_bounds__(256) void qk_kernel(
    const bf16* __restrict__ Qr, const bf16* __restrict__ Kr,
    const u64* __restrict__ Mbits, float* __restrict__ out) {
    const int z = blockIdx.z;               // b*T + t
    const int b = z / Tsz;
    const int i0 = blockIdx.y * 64, j0 = blockIdx.x * 64;
    float* ob = out + (size_t)z * Lsz * Lsz;

    if (blockIdx.y > blockIdx.x) {          // below diagonal: -1e12 fill
        const f32x4 f = {-1e12f, -1e12f, -1e12f, -1e12f};
#pragma unroll
        for (int s = 0; s < 4; ++s) {
            const int idx = s * 256 + threadIdx.x;
            const int r = idx >> 4, c = (idx & 15) << 2;
            *(f32x4*)(ob + (size_t)(i0 + r) * Lsz + j0 + c) = f;
        }
        return;
    }

    const int wave = threadIdx.x >> 6, lane = threadIdx.x & 63;
    const int l15 = lane & 15, hi = lane >> 4;
    const bf16* Qb = Qr + (size_t)z * Lsz * Asz;
    const bf16* Kb = Kr + (size_t)z * Lsz * Asz;

    const int irow = i0 + wave * 16 + l15;
    const bf16x8 q0 = *(const bf16x8*)(Qb + (size_t)irow * 64 + hi * 8);
    const bf16x8 q1 = *(const bf16x8*)(Qb + (size_t)irow * 64 + 32 + hi * 8);

    f32x4 acc[4] = {};
#pragma unroll
    for (int ct = 0; ct < 4; ++ct) {
        const int jrow = j0 + ct * 16 + l15;
        bf16x8 k0 = *(const bf16x8*)(Kb + (size_t)jrow * 64 + hi * 8);
        bf16x8 k1 = *(const bf16x8*)(Kb + (size_t)jrow * 64 + 32 + hi * 8);
        acc[ct] = __builtin_amdgcn_mfma_f32_16x16x32_bf16(k0, q0, acc[ct], 0, 0, 0);
        acc[ct] = __builtin_amdgcn_mfma_f32_16x16x32_bf16(k1, q1, acc[ct], 0, 0, 0);
    }

    const u64 jb = Mbits[b * 8 + (j0 >> 6)];
    const u64 ib = Mbits[b * 8 + (i0 >> 6)];
    const bool mi = (ib >> (wave * 16 + l15)) & 1;

#pragma unroll
    for (int ct = 0; ct < 4; ++ct) {
        const int jbase = ct * 16 + hi * 4;
        f32x4 v;
#pragma unroll
        for (int r = 0; r < 4; ++r) {
            const int j = j0 + jbase + r;
            const bool keep = mi && ((jb >> (jbase + r)) & 1) && (irow <= j);
            v[r] = keep ? acc[ct][r] : -1e12f;
        }
        *(f32x4*)(ob + (size_t)irow * Lsz + j0 + jbase) = v;
    }
}

extern "C" void kernel_launch(void* const* d_in, const int* in_sizes, int n_in,
                              void* d_out, int out_size, void* d_ws, size_t ws_size,
                              hipStream_t stream) {
    const float* in_f  = (const float*)d_in[0];
    const int*   amask = (const int*)d_in[1];
    const float* W     = (const float*)d_in[2];
    const float* bias  = (const float*)d_in[3];
    float* out = (float*)d_out;

    char* ws = (char*)d_ws;
    bf16*  Abf   = (bf16*)ws;                                // 12,582,912 B
    bf16*  Wt    = (bf16*)(ws + 12582912);                   //  2,359,296 B
    bf16*  Qr    = (bf16*)(ws + 14942208);                   // 12,582,912 B
    bf16*  Kr    = (bf16*)(ws + 27525120);                   // 12,582,912 B
    float* Tc    = (float*)(ws + 40108032);                  //    131,072 B
    float* Ts    = (float*)(ws + 40239104);                  //    131,072 B
    u64*   Mbits = (u64*)(ws + 40370176);                    //      1,024 B

    prep_kernel<<<6880, 256, 0, stream>>>(in_f, W, amask, Abf, Wt, Tc, Ts, Mbits);
    proj_kernel<<<192, 512, 0, stream>>>(Abf, Wt, bias, Tc, Ts, Qr, Kr);
    qk_kernel<<<dim3(8, 8, Bsz * Tsz), 256, 0, stream>>>(Qr, Kr, Mbits, out);
}

// Round 11
// 92.234 us; speedup vs baseline: 1.2638x; 1.2638x over previous
//
#include <hip/hip_runtime.h>
#include <hip/hip_bf16.h>

// Problem constants
#define Bsz 16
#define Lsz 512
#define Dsz 768
#define Tsz 12
#define Asz 64
#define N1  1536   // Tsz*Asz*2
#define Msz 8192   // Bsz*Lsz

typedef __bf16 bf16;
typedef bf16 bf16x2 __attribute__((ext_vector_type(2)));
typedef bf16 bf16x4 __attribute__((ext_vector_type(4)));
typedef bf16 bf16x8 __attribute__((ext_vector_type(8)));
typedef float f32x4 __attribute__((ext_vector_type(4)));
typedef unsigned long long u64;

__device__ inline void load_lds16(const bf16* g, bf16* l) {
    __builtin_amdgcn_global_load_lds((const __attribute__((address_space(1))) void*)g,
                                     (__attribute__((address_space(3))) void*)l, 16, 0, 0);
}

// ---- kernel 1: prep (cvt_input | cvt_w | rope tables | mask bits)
//      + all 28x192 below-diagonal -1e12 tiles (1344 fill blocks; aggregate-rate) ----
__global__ __launch_bounds__(256) void prep_fill_kernel(
    const float* __restrict__ in, const float* __restrict__ W,
    const int* __restrict__ mask,
    bf16* __restrict__ Abf, bf16* __restrict__ Wt,
    float* __restrict__ Tc, float* __restrict__ Ts, u64* __restrict__ Mbits,
    float* __restrict__ out) {
    int blk = blockIdx.x;
    if (blk < 6144) {                       // cvt_input: 8192*768/4 threads
        int i = blk * 256 + threadIdx.x;
        float4 v = ((const float4*)in)[i];
        bf16x4 o;
        o[0] = (bf16)v.x; o[1] = (bf16)v.y; o[2] = (bf16)v.z; o[3] = (bf16)v.w;
        ((bf16x4*)Abf)[i] = o;
    } else if (blk < 6720) {                // cvt_w: N1*(Dsz/8) threads
        int tid = (blk - 6144) * 256 + threadIdx.x;
        int n  = tid % N1;
        int k0 = (tid / N1) * 8;
        bf16x8 o;
#pragma unroll
        for (int j = 0; j < 8; ++j) o[j] = (bf16)W[(size_t)(k0 + j) * N1 + n];
        *(bf16x8*)(Wt + (size_t)n * Dsz + k0) = o;
    } else if (blk < 6848) {                // rope tables: 512*64 threads
        int tid = (blk - 6720) * 256 + threadIdx.x;
        int l = tid >> 6, a = tid & 63;
        float theta = expf(-0.28782313662425575f * (float)(a >> 1));  // 10000^(-(a>>1)/32)
        float pe = (float)l * theta;
        float s, c;
        sincosf(pe, &s, &c);
        Tc[tid] = c; Ts[tid] = s;
    } else if (blk < 6880) {                // mask bits: 16*512 threads
        int tid = (blk - 6848) * 256 + threadIdx.x;
        u64 bal = __ballot(mask[tid] > 0);
        if ((tid & 63) == 0) Mbits[tid >> 6] = bal;
    } else {                                // fills: 1344 blocks = 192 z x 7 chunks
        const int fb = blk - 6880;
        const int zz = fb / 7, chunk = fb % 7;   // chunk = 4 tiles of the 28
        float* ob = out + (size_t)zz * Lsz * Lsz;
        const f32x4 f = {-1e12f, -1e12f, -1e12f, -1e12f};
        // nibble tables for the (it>jt) tile enumeration p=0..27
        const u64 itlo = 0x6555554444333221ull, ithi = 0x0000777777766666ull;
        const u64 jtlo = 0x0432103210210100ull, jthi = 0x0000654321054321ull;
        const int r = threadIdx.x >> 2, cc = (threadIdx.x & 3) << 4;
#pragma unroll
        for (int k = 0; k < 4; ++k) {
            const int p = chunk * 4 + k;
            const int it = (int)(((p < 16) ? (itlo >> (4 * p)) : (ithi >> (4 * (p - 16)))) & 15);
            const int jt = (int)(((p < 16) ? (jtlo >> (4 * p)) : (jthi >> (4 * (p - 16)))) & 15);
            float* base = ob + (size_t)(it * 64 + r) * Lsz + jt * 64 + cc;
            *(f32x4*)(base)      = f;
            *(f32x4*)(base + 4)  = f;
            *(f32x4*)(base + 8)  = f;
            *(f32x4*)(base + 12) = f;
        }
    }
}

__device__ __forceinline__ void rope_row(bf16* P, const float* tc, const float* ts) {
    float v[64];
#pragma unroll
    for (int c8 = 0; c8 < 8; ++c8) {
        bf16x8 x = *(const bf16x8*)(P + c8 * 8);
#pragma unroll
        for (int j = 0; j < 8; ++j) v[c8 * 8 + j] = (float)x[j];
    }
#pragma unroll
    for (int c8 = 0; c8 < 8; ++c8) {
        bf16x8 o;
#pragma unroll
        for (int j = 0; j < 8; ++j) {
            const int a  = c8 * 8 + j;
            const int a2 = (a < 32) ? (2 * a + 1) : (2 * (a - 32));
            const float sg = (a < 32) ? -1.f : 1.f;
            o[j] = (bf16)(v[a] * tc[a] + sg * v[a2] * ts[a]);
        }
        *(bf16x8*)(P + c8 * 8) = o;
    }
}

// ---- kernel 2: fused proj+rope+QK, upper (jt>=it) tiles only. 192 blocks x 512 thr.
// Staging XOR-swizzle: LDS slot c of row r holds global chunk c^((r>>1)&3)
// (pre-swizzled global source, linear LDS dest); frag reads use hi^((l15>>1)&3).
#define PBUF 40960   // A 32768 + W 8192 per staging buffer
__global__ __launch_bounds__(512) void fused_kernel(
    const bf16* __restrict__ Abf, const bf16* __restrict__ Wt,
    const float* __restrict__ bias,
    const float* __restrict__ Tc, const float* __restrict__ Ts,
    const u64* __restrict__ Mbits, float* __restrict__ out) {
    __shared__ char smem[147456];
    bf16* Xq = (bf16*)smem;                  // [512][72]
    bf16* Xk = (bf16*)(smem + 73728);        // [512][72]

    const int bid = blockIdx.x;
    const int tid = threadIdx.x;

    const int z  = (bid & 7) * 24 + (bid >> 3);   // XCD-chunked
    const int b  = z / Tsz, th = z % Tsz;

    const int wave = tid >> 6, lane = tid & 63;
    const int l15 = lane & 15, hi = lane >> 4;
    const int wm = wave >> 1, wn = wave & 1;

    const bf16* Ab = Abf + (size_t)b * Lsz * Dsz;
    const bf16* Wb = Wt + (size_t)th * 128 * Dsz;
    float* ob = out + (size_t)z * Lsz * Lsz;
    const int lq = lane >> 2;
    const int schunk = ((lane & 3) ^ ((lane >> 3) & 3)) * 8;   // swizzled src chunk
    const int dchunk = (lane & 3) * 8;                          // linear dest chunk
    const int koff = (hi ^ ((l15 >> 1) & 3)) * 16;              // swizzled frag read

    // ---------- phase 1: projection 512x128 = A @ W_head^T ----------
    f32x4 acc[8][4] = {};

#define PSTAGE(buf, kk)                                                         \
    do {                                                                        \
        bf16* As = (bf16*)(smem + (buf) * PBUF);                                \
        bf16* Ws = (bf16*)(smem + (buf) * PBUF + 32768);                        \
        _Pragma("unroll")                                                       \
        for (int i = 0; i < 4; ++i) {                                           \
            int ra = wave * 64 + i * 16 + lq;                                   \
            load_lds16(Ab + (size_t)ra * Dsz + (kk) + schunk, As + ra * 32 + dchunk); \
        }                                                                       \
        int rw = wave * 16 + lq;                                                \
        load_lds16(Wb + (size_t)rw * Dsz + (kk) + schunk, Ws + rw * 32 + dchunk); \
    } while (0)

    PSTAGE(0, 0);
    PSTAGE(1, 32);
    asm volatile("s_waitcnt vmcnt(5)" ::: "memory");
    __builtin_amdgcn_s_barrier();

    int cur = 0;
    for (int t = 0; t < 24; ++t) {
        int stg = cur + 2; if (stg >= 3) stg -= 3;
        if (t + 2 < 24) PSTAGE(stg, (t + 2) * 32);

        const char* As = smem + cur * PBUF;
        const char* Ws = smem + cur * PBUF + 32768;
        bf16x8 af[8], bw[4];
#pragma unroll
        for (int mf = 0; mf < 8; ++mf)
            af[mf] = *(const bf16x8*)(As + (wm * 128 + mf * 16 + l15) * 64 + koff);
#pragma unroll
        for (int nf = 0; nf < 4; ++nf)
            bw[nf] = *(const bf16x8*)(Ws + (wn * 64 + nf * 16 + l15) * 64 + koff);
#pragma unroll
        for (int mf = 0; mf < 8; ++mf)
#pragma unroll
            for (int nf = 0; nf < 4; ++nf)
                acc[mf][nf] = __builtin_amdgcn_mfma_f32_16x16x32_bf16(af[mf], bw[nf], acc[mf][nf], 0, 0, 0);

        if (t + 1 < 24) {
            if (t + 2 < 24) asm volatile("s_waitcnt vmcnt(5)" ::: "memory");
            else            asm volatile("s_waitcnt vmcnt(0)" ::: "memory");
            __builtin_amdgcn_s_barrier();
        }
        cur = cur + 1; if (cur >= 3) cur -= 3;
    }
#undef PSTAGE
    __syncthreads();    // staging dead; smem becomes Xq/Xk planes

    // ---------- phase 2: acc (+bias) -> q/k planes ----------
    // C/D: col=wn*64+nf*16+l15, row=wm*128+mf*16+hi*4+r. col c: even->q, odd->k.
    {
        const int r0 = hi * 4;
#pragma unroll
        for (int nf = 0; nf < 4; ++nf) {
            const int c = wn * 64 + nf * 16 + l15;
            const float bv = bias[th * 128 + c];
            bf16* P = (c & 1) ? Xk : Xq;
            const int a = c >> 1;
#pragma unroll
            for (int mf = 0; mf < 8; ++mf) {
                const int rw = wm * 128 + mf * 16 + r0;
#pragma unroll
                for (int r = 0; r < 4; ++r)
                    P[(rw + r) * 72 + a] = (bf16)(acc[mf][nf][r] + bv);
            }
        }
    }
    __syncthreads();

    // ---------- phase 3: rope in place (thread = row l) ----------
    rope_row(Xq + tid * 72, Tc + tid * 64, Ts + tid * 64);
    rope_row(Xk + tid * 72, Tc + tid * 64, Ts + tid * 64);
    __syncthreads();

    // ---------- phase 4: QK^T + mask, upper tiles only ----------
    const u64* mb = Mbits + b * 8;
#pragma unroll
    for (int s = 0; s < 8; ++s) {
        const int it = s, jt = (wave - s) & 7;    // (it+jt)%8==wave
        if (jt < it) continue;
        const int i0 = it * 64, j0 = jt * 64;
        const u64 jb = mb[jt], ib = mb[it];
        bf16x8 k0[4], k1[4];
#pragma unroll
        for (int ct = 0; ct < 4; ++ct) {
            const int jr = j0 + ct * 16 + l15;
            k0[ct] = *(const bf16x8*)(Xk + jr * 72 + hi * 8);
            k1[ct] = *(const bf16x8*)(Xk + jr * 72 + 32 + hi * 8);
        }
#pragma unroll
        for (int is = 0; is < 4; ++is) {
            const int ir = i0 + is * 16 + l15;
            bf16x8 q0 = *(const bf16x8*)(Xq + ir * 72 + hi * 8);
            bf16x8 q1 = *(const bf16x8*)(Xq + ir * 72 + 32 + hi * 8);
            f32x4 a4[4] = {};
#pragma unroll
            for (int ct = 0; ct < 4; ++ct) {
                a4[ct] = __builtin_amdgcn_mfma_f32_16x16x32_bf16(k0[ct], q0, a4[ct], 0, 0, 0);
                a4[ct] = __builtin_amdgcn_mfma_f32_16x16x32_bf16(k1[ct], q1, a4[ct], 0, 0, 0);
            }
            const bool mi = (ib >> (is * 16 + l15)) & 1;
#pragma unroll
            for (int ct = 0; ct < 4; ++ct) {
                const int jbase = ct * 16 + hi * 4;
                f32x4 vv;
#pragma unroll
                for (int r = 0; r < 4; ++r) {
                    const int j = j0 + jbase + r;
                    const bool keep = mi && ((jb >> (jbase + r)) & 1) && (ir <= j);
                    vv[r] = keep ? a4[ct][r] : -1e12f;
                }
                *(f32x4*)(ob + (size_t)ir * Lsz + j0 + jbase) = vv;
            }
        }
    }
}

extern "C" void kernel_launch(void* const* d_in, const int* in_sizes, int n_in,
                              void* d_out, int out_size, void* d_ws, size_t ws_size,
                              hipStream_t stream) {
    const float* in_f  = (const float*)d_in[0];
    const int*   amask = (const int*)d_in[1];
    const float* W     = (const float*)d_in[2];
    const float* bias  = (const float*)d_in[3];
    float* out = (float*)d_out;

    char* ws = (char*)d_ws;
    bf16*  Abf   = (bf16*)ws;                                // 12,582,912 B
    bf16*  Wt    = (bf16*)(ws + 12582912);                   //  2,359,296 B
    float* Tc    = (float*)(ws + 14942208);                  //    131,072 B
    float* Ts    = (float*)(ws + 15073280);                  //    131,072 B
    u64*   Mbits = (u64*)(ws + 15204352);                    //      1,024 B

    // prep + all below-diagonal fills (6880 prep blocks + 1344 fill blocks)
    prep_fill_kernel<<<8224, 256, 0, stream>>>(in_f, W, amask, Abf, Wt, Tc, Ts, Mbits, out);
    // proj + rope + upper-tile QK
    fused_kernel<<<192, 512, 0, stream>>>(Abf, Wt, bias, Tc, Ts, Mbits, out);
}

// Round 12
// 70.815 us; speedup vs baseline: 1.6461x; 1.3025x over previous
//
#include <hip/hip_runtime.h>
#include <hip/hip_bf16.h>

// Problem constants
#define Bsz 16
#define Lsz 512
#define Dsz 768
#define Tsz 12
#define Asz 64
#define N1  1536   // Tsz*Asz*2
#define Msz 8192   // Bsz*Lsz

typedef __bf16 bf16;
typedef bf16 bf16x2 __attribute__((ext_vector_type(2)));
typedef bf16 bf16x4 __attribute__((ext_vector_type(4)));
typedef bf16 bf16x8 __attribute__((ext_vector_type(8)));
typedef float f32x4 __attribute__((ext_vector_type(4)));
typedef unsigned long long u64;

__device__ inline void load_lds16(const bf16* g, bf16* l) {
    __builtin_amdgcn_global_load_lds((const __attribute__((address_space(1))) void*)g,
                                     (__attribute__((address_space(3))) void*)l, 16, 0, 0);
}

// ---- prep: cvt_input | cvt_w | rope tables | mask bits ----
__global__ __launch_bounds__(256) void prep_kernel(
    const float* __restrict__ in, const float* __restrict__ W,
    const int* __restrict__ mask,
    bf16* __restrict__ Abf, bf16* __restrict__ Wt,
    float* __restrict__ Tc, float* __restrict__ Ts, u64* __restrict__ Mbits) {
    int blk = blockIdx.x;
    if (blk < 6144) {                       // cvt_input: 8192*768/4 threads
        int i = blk * 256 + threadIdx.x;
        float4 v = ((const float4*)in)[i];
        bf16x4 o;
        o[0] = (bf16)v.x; o[1] = (bf16)v.y; o[2] = (bf16)v.z; o[3] = (bf16)v.w;
        ((bf16x4*)Abf)[i] = o;
    } else if (blk < 6720) {                // cvt_w: N1*(Dsz/8) threads
        int tid = (blk - 6144) * 256 + threadIdx.x;
        int n  = tid % N1;
        int k0 = (tid / N1) * 8;
        bf16x8 o;
#pragma unroll
        for (int j = 0; j < 8; ++j) o[j] = (bf16)W[(size_t)(k0 + j) * N1 + n];
        *(bf16x8*)(Wt + (size_t)n * Dsz + k0) = o;
    } else if (blk < 6848) {                // rope tables: 512*64 threads
        int tid = (blk - 6720) * 256 + threadIdx.x;
        int l = tid >> 6, a = tid & 63;
        float theta = expf(-0.28782313662425575f * (float)(a >> 1));  // 10000^(-(a>>1)/32)
        float pe = (float)l * theta;
        float s, c;
        sincosf(pe, &s, &c);
        Tc[tid] = c; Ts[tid] = s;
    } else {                                // mask bits: 16*512 threads
        int tid = (blk - 6848) * 256 + threadIdx.x;
        u64 bal = __ballot(mask[tid] > 0);
        if ((tid & 63) == 0) Mbits[tid >> 6] = bal;
    }
}

__device__ __forceinline__ void rope_row(bf16* P, const float* tc, const float* ts) {
    float v[64];
#pragma unroll
    for (int c8 = 0; c8 < 8; ++c8) {
        bf16x8 x = *(const bf16x8*)(P + c8 * 8);
#pragma unroll
        for (int j = 0; j < 8; ++j) v[c8 * 8 + j] = (float)x[j];
    }
#pragma unroll
    for (int c8 = 0; c8 < 8; ++c8) {
        bf16x8 o;
#pragma unroll
        for (int j = 0; j < 8; ++j) {
            const int a  = c8 * 8 + j;
            const int a2 = (a < 32) ? (2 * a + 1) : (2 * (a - 32));
            const float sg = (a < 32) ? -1.f : 1.f;
            o[j] = (bf16)(v[a] * tc[a] + sg * v[a2] * ts[a]);
        }
        *(bf16x8*)(P + c8 * 8) = o;
    }
}

// ---- fused kernel, store-balanced (~786 KB stores per block):
//   blocks 0..191 (compute): proj (with 12 lower fill tiles interleaved into
//     the K-loop: 1 f32x4 store/thread/iter) + rope + 36 upper QK tiles.
//   blocks 192..255 (fill): 16 lower tiles x 3 z each.
// vmcnt accounting with interleaved store (stores share vmcnt, in-order):
//   prologue vmcnt(5); steady vmcnt(6) = [1 store + 5 t+2 loads] outstanding
//   => t+1 loads landed; tail vmcnt(1).
#define PBUF 40960   // A 32768 + W 8192 per staging buffer
__global__ __launch_bounds__(512) void fused_kernel(
    const bf16* __restrict__ Abf, const bf16* __restrict__ Wt,
    const float* __restrict__ bias,
    const float* __restrict__ Tc, const float* __restrict__ Ts,
    const u64* __restrict__ Mbits, float* __restrict__ out) {
    __shared__ char smem[147456];
    const int bid = blockIdx.x;
    const int tid = threadIdx.x;

    if (bid >= 192) {
        // -------- fill role: tiles p=12..27 of 3 z each (16 x 16KB x 3) --------
        const int w = bid - 192;
        const f32x4 f = {-1e12f, -1e12f, -1e12f, -1e12f};
        const u64 itt = 0x7777777666666555ull, jtt = 0x6543210543210432ull;
        for (int zz = 0; zz < 3; ++zz) {
            float* ob = out + (size_t)(w * 3 + zz) * Lsz * Lsz;
#pragma unroll
            for (int p = 0; p < 16; ++p) {
                const int it = (int)((itt >> (4 * p)) & 15);
                const int jt = (int)((jtt >> (4 * p)) & 15);
#pragma unroll
                for (int rep = 0; rep < 2; ++rep) {
                    const int idx = rep * 512 + tid;
                    const int r = idx >> 4, c = (idx & 15) << 2;
                    *(f32x4*)(ob + (size_t)(it * 64 + r) * Lsz + jt * 64 + c) = f;
                }
            }
        }
        return;
    }

    // ---------------- compute role ----------------
    bf16* Xq = (bf16*)smem;                  // [512][72]
    bf16* Xk = (bf16*)(smem + 73728);        // [512][72]

    const int z  = (bid & 7) * 24 + (bid >> 3);   // XCD-chunked
    const int b  = z / Tsz, th = z % Tsz;

    const int wave = tid >> 6, lane = tid & 63;
    const int l15 = lane & 15, hi = lane >> 4;
    const int wm = wave >> 1, wn = wave & 1;

    const bf16* Ab = Abf + (size_t)b * Lsz * Dsz;
    const bf16* Wb = Wt + (size_t)th * 128 * Dsz;
    float* ob = out + (size_t)z * Lsz * Lsz;
    const int lq = lane >> 2;
    const int schunk = ((lane & 3) ^ ((lane >> 3) & 3)) * 8;   // swizzled src chunk
    const int dchunk = (lane & 3) * 8;                          // linear dest chunk
    const int koff = (hi ^ ((l15 >> 1) & 3)) * 16;              // swizzled frag read

    // ---------- phase 1: projection + interleaved fill stores ----------
    f32x4 acc[8][4] = {};
    const f32x4 fneg = {-1e12f, -1e12f, -1e12f, -1e12f};
    const u64 citt = 0x554444333221ull, cjtt = 0x103210210100ull;  // p=0..11
    const int fr = tid >> 4, fc = (tid & 15) << 2;                 // within half-tile

#define PSTAGE(buf, kk)                                                         \
    do {                                                                        \
        bf16* As = (bf16*)(smem + (buf) * PBUF);                                \
        bf16* Ws = (bf16*)(smem + (buf) * PBUF + 32768);                        \
        _Pragma("unroll")                                                       \
        for (int i = 0; i < 4; ++i) {                                           \
            int ra = wave * 64 + i * 16 + lq;                                   \
            load_lds16(Ab + (size_t)ra * Dsz + (kk) + schunk, As + ra * 32 + dchunk); \
        }                                                                       \
        int rw = wave * 16 + lq;                                                \
        load_lds16(Wb + (size_t)rw * Dsz + (kk) + schunk, Ws + rw * 32 + dchunk); \
    } while (0)

    PSTAGE(0, 0);
    PSTAGE(1, 32);
    asm volatile("s_waitcnt vmcnt(5)" ::: "memory");
    __builtin_amdgcn_s_barrier();

    int cur = 0;
    for (int t = 0; t < 24; ++t) {
        // interleaved fill store: tile p=t>>1, half h=t&1 (12 tiles over 24 iters)
        {
            const int p = t >> 1, h = t & 1;
            const int it = (int)((citt >> (4 * p)) & 15);
            const int jt = (int)((cjtt >> (4 * p)) & 15);
            const int r = h * 32 + fr;
            *(f32x4*)(ob + (size_t)(it * 64 + r) * Lsz + jt * 64 + fc) = fneg;
        }

        int stg = cur + 2; if (stg >= 3) stg -= 3;
        if (t + 2 < 24) PSTAGE(stg, (t + 2) * 32);

        const char* As = smem + cur * PBUF;
        const char* Ws = smem + cur * PBUF + 32768;
        bf16x8 af[8], bw[4];
#pragma unroll
        for (int mf = 0; mf < 8; ++mf)
            af[mf] = *(const bf16x8*)(As + (wm * 128 + mf * 16 + l15) * 64 + koff);
#pragma unroll
        for (int nf = 0; nf < 4; ++nf)
            bw[nf] = *(const bf16x8*)(Ws + (wn * 64 + nf * 16 + l15) * 64 + koff);
#pragma unroll
        for (int mf = 0; mf < 8; ++mf)
#pragma unroll
            for (int nf = 0; nf < 4; ++nf)
                acc[mf][nf] = __builtin_amdgcn_mfma_f32_16x16x32_bf16(af[mf], bw[nf], acc[mf][nf], 0, 0, 0);

        if (t + 1 < 24) {
            if (t + 2 < 24)      asm volatile("s_waitcnt vmcnt(6)" ::: "memory");
            else                 asm volatile("s_waitcnt vmcnt(1)" ::: "memory");
            __builtin_amdgcn_s_barrier();
        }
        cur = cur + 1; if (cur >= 3) cur -= 3;
    }
#undef PSTAGE
    __syncthreads();    // drains all vm ops; staging dead; smem becomes planes

    // ---------- phase 2: acc (+bias) -> q/k planes ----------
    // C/D: col=wn*64+nf*16+l15, row=wm*128+mf*16+hi*4+r. col c: even->q, odd->k.
    {
        const int r0 = hi * 4;
#pragma unroll
        for (int nf = 0; nf < 4; ++nf) {
            const int c = wn * 64 + nf * 16 + l15;
            const float bv = bias[th * 128 + c];
            bf16* P = (c & 1) ? Xk : Xq;
            const int a = c >> 1;
#pragma unroll
            for (int mf = 0; mf < 8; ++mf) {
                const int rw = wm * 128 + mf * 16 + r0;
#pragma unroll
                for (int r = 0; r < 4; ++r)
                    P[(rw + r) * 72 + a] = (bf16)(acc[mf][nf][r] + bv);
            }
        }
    }
    __syncthreads();

    // ---------- phase 3: rope in place (thread = row l) ----------
    rope_row(Xq + tid * 72, Tc + tid * 64, Ts + tid * 64);
    rope_row(Xk + tid * 72, Tc + tid * 64, Ts + tid * 64);
    __syncthreads();

    // ---------- phase 4: QK^T + mask, upper tiles only ----------
    const u64* mb = Mbits + b * 8;
#pragma unroll
    for (int s = 0; s < 8; ++s) {
        const int it = s, jt = (wave - s) & 7;    // (it+jt)%8==wave
        if (jt < it) continue;
        const int i0 = it * 64, j0 = jt * 64;
        const u64 jb = mb[jt], ib = mb[it];
        bf16x8 k0[4], k1[4];
#pragma unroll
        for (int ct = 0; ct < 4; ++ct) {
            const int jr = j0 + ct * 16 + l15;
            k0[ct] = *(const bf16x8*)(Xk + jr * 72 + hi * 8);
            k1[ct] = *(const bf16x8*)(Xk + jr * 72 + 32 + hi * 8);
        }
#pragma unroll
        for (int is = 0; is < 4; ++is) {
            const int ir = i0 + is * 16 + l15;
            bf16x8 q0 = *(const bf16x8*)(Xq + ir * 72 + hi * 8);
            bf16x8 q1 = *(const bf16x8*)(Xq + ir * 72 + 32 + hi * 8);
            f32x4 a4[4] = {};
#pragma unroll
            for (int ct = 0; ct < 4; ++ct) {
                a4[ct] = __builtin_amdgcn_mfma_f32_16x16x32_bf16(k0[ct], q0, a4[ct], 0, 0, 0);
                a4[ct] = __builtin_amdgcn_mfma_f32_16x16x32_bf16(k1[ct], q1, a4[ct], 0, 0, 0);
            }
            const bool mi = (ib >> (is * 16 + l15)) & 1;
#pragma unroll
            for (int ct = 0; ct < 4; ++ct) {
                const int jbase = ct * 16 + hi * 4;
                f32x4 vv;
#pragma unroll
                for (int r = 0; r < 4; ++r) {
                    const int j = j0 + jbase + r;
                    const bool keep = mi && ((jb >> (jbase + r)) & 1) && (ir <= j);
                    vv[r] = keep ? a4[ct][r] : -1e12f;
                }
                *(f32x4*)(ob + (size_t)ir * Lsz + j0 + jbase) = vv;
            }
        }
    }
}

extern "C" void kernel_launch(void* const* d_in, const int* in_sizes, int n_in,
                              void* d_out, int out_size, void* d_ws, size_t ws_size,
                              hipStream_t stream) {
    const float* in_f  = (const float*)d_in[0];
    const int*   amask = (const int*)d_in[1];
    const float* W     = (const float*)d_in[2];
    const float* bias  = (const float*)d_in[3];
    float* out = (float*)d_out;

    char* ws = (char*)d_ws;
    bf16*  Abf   = (bf16*)ws;                                // 12,582,912 B
    bf16*  Wt    = (bf16*)(ws + 12582912);                   //  2,359,296 B
    float* Tc    = (float*)(ws + 14942208);                  //    131,072 B
    float* Ts    = (float*)(ws + 15073280);                  //    131,072 B
    u64*   Mbits = (u64*)(ws + 15204352);                    //      1,024 B

    prep_kernel<<<6880, 256, 0, stream>>>(in_f, W, amask, Abf, Wt, Tc, Ts, Mbits);
    fused_kernel<<<256, 512, 0, stream>>>(Abf, Wt, bias, Tc, Ts, Mbits, out);
}